// Round 5
// baseline (189.047 us; speedup 1.0000x reference)
//
#include <hip/hip_runtime.h>
#include <hip/hip_bf16.h>
#include <float.h>
#include <math.h>

// BatchHardTripletLoss on MI355X — bf16x3 MFMA gram, NO-LDS direct-from-L2
// fragment loads (zero barriers in k-loop), XCD-swizzled triangular tiles,
// fused last-block finalize. 2 launches.
// batch = concat(h1,h2) : [4096,512] fp32 -> hi/lo bf16 split.
// dot(a,b) ~= hi.hi + hi.lo + lo.hi (fp32 MFMA accum) — bitwise-validated R3/R4.

#define NTOT 4096
#define NHALF 2048
#define DIM 512
#define BM 128
#define KSTEPS 16                      // 512 / 32
#define NTILE (NTOT / BM)              // 32
#define NTRI (NTILE * (NTILE + 1) / 2) // 528 = 8 * 66
#define FLTMAX 3.402823466e+38f

typedef __attribute__((ext_vector_type(8))) short bf16x8;
typedef __attribute__((ext_vector_type(4))) float f32x4;

__device__ __forceinline__ ushort bf16hi_bits(float x, float* hf) {
    __hip_bfloat16 b = __float2bfloat16(x);
    *hf = __bfloat162float(b);
    return *reinterpret_cast<ushort*>(&b);
}
__device__ __forceinline__ ushort bf16_bits(float x) {
    __hip_bfloat16 b = __float2bfloat16(x);
    return *reinterpret_cast<ushort*>(&b);
}

// One wave per row-pair i: sq, exact partner d2, hi/lo split, minb init, cnt zero.
__global__ __launch_bounds__(256) void prep_kernel(const float* __restrict__ h1,
                                                   const float* __restrict__ h2,
                                                   float* __restrict__ sq,
                                                   float* __restrict__ hp_d2,
                                                   unsigned int* __restrict__ minb,
                                                   unsigned int* __restrict__ cnt,
                                                   ushort* __restrict__ hi,
                                                   ushort* __restrict__ lo) {
    if (blockIdx.x == 0 && threadIdx.x == 0) *cnt = 0u;
    int wv = threadIdx.x >> 6, lane = threadIdx.x & 63;
    int i = blockIdx.x * 4 + wv;
    if (i >= NHALF) return;
    if (lane < 2) minb[i + lane * NHALF] = 0x7F800000u;  // +inf bits

    const float4* r1 = (const float4*)(h1 + (size_t)i * DIM);
    const float4* r2 = (const float4*)(h2 + (size_t)i * DIM);
    float4 a0 = r1[lane], a1 = r1[lane + 64];
    float4 b0 = r2[lane], b1 = r2[lane + 64];

    float s1 = a0.x*a0.x + a0.y*a0.y + a0.z*a0.z + a0.w*a0.w
             + a1.x*a1.x + a1.y*a1.y + a1.z*a1.z + a1.w*a1.w;
    float s2 = b0.x*b0.x + b0.y*b0.y + b0.z*b0.z + b0.w*b0.w
             + b1.x*b1.x + b1.y*b1.y + b1.z*b1.z + b1.w*b1.w;
    float s12 = a0.x*b0.x + a0.y*b0.y + a0.z*b0.z + a0.w*b0.w
              + a1.x*b1.x + a1.y*b1.y + a1.z*b1.z + a1.w*b1.w;

    {
        float f[8] = {a0.x, a0.y, a0.z, a0.w, a1.x, a1.y, a1.z, a1.w};
        float g[8] = {b0.x, b0.y, b0.z, b0.w, b1.x, b1.y, b1.z, b1.w};
        ushort4 h4, l4v; float hf;
        #pragma unroll
        for (int half = 0; half < 2; ++half) {
            float* p = f + half * 4;
            h4.x = bf16hi_bits(p[0], &hf); l4v.x = bf16_bits(p[0] - hf);
            h4.y = bf16hi_bits(p[1], &hf); l4v.y = bf16_bits(p[1] - hf);
            h4.z = bf16hi_bits(p[2], &hf); l4v.z = bf16_bits(p[2] - hf);
            h4.w = bf16hi_bits(p[3], &hf); l4v.w = bf16_bits(p[3] - hf);
            size_t off = (size_t)i * DIM + half * 256 + lane * 4;
            *(ushort4*)(hi + off) = h4;
            *(ushort4*)(lo + off) = l4v;
        }
        #pragma unroll
        for (int half = 0; half < 2; ++half) {
            float* p = g + half * 4;
            h4.x = bf16hi_bits(p[0], &hf); l4v.x = bf16_bits(p[0] - hf);
            h4.y = bf16hi_bits(p[1], &hf); l4v.y = bf16_bits(p[1] - hf);
            h4.z = bf16hi_bits(p[2], &hf); l4v.z = bf16_bits(p[2] - hf);
            h4.w = bf16hi_bits(p[3], &hf); l4v.w = bf16_bits(p[3] - hf);
            size_t off = (size_t)(i + NHALF) * DIM + half * 256 + lane * 4;
            *(ushort4*)(hi + off) = h4;
            *(ushort4*)(lo + off) = l4v;
        }
    }

    #pragma unroll
    for (int m = 1; m < 64; m <<= 1) {
        s1  += __shfl_xor(s1, m);
        s2  += __shfl_xor(s2, m);
        s12 += __shfl_xor(s12, m);
    }
    if (lane == 0) {
        sq[i] = s1;
        sq[i + NHALF] = s2;
        float pd = s1 + s2 - 2.0f * s12;
        hp_d2[i] = pd;
        hp_d2[i + NHALF] = pd;
    }
}

// 528 triangular 128x128 tiles; 4 waves (2x2), wave tile 64x64 (4x4 frags of
// 16x16x32 bf16, 3 MFMA each). Fragments loaded DIRECTLY from global (L2):
// 16 x 16B loads per phase per lane at full-sector addresses; no LDS, no
// barriers in the k-loop. XCD swizzle: consecutive triangular indices grouped
// per XCD so A-panels stay hot in the 4 MiB per-XCD L2.
__global__ __launch_bounds__(256, 3) void pairmin_mfma(const ushort* __restrict__ hi,
                                                       const ushort* __restrict__ lo,
                                                       const float* __restrict__ sq,
                                                       const float* __restrict__ hp_d2,
                                                       unsigned int* __restrict__ minb,
                                                       unsigned int* __restrict__ cnt,
                                                       float* __restrict__ out) {
    __shared__ float red[5 * 256];
    __shared__ unsigned int finflag;

    // bijective XCD swizzle: 528 = 8 * 66
    int bid = blockIdx.x;
    int t = (bid & 7) * (NTRI / 8) + (bid >> 3);
    int bi = 0, rem = NTILE;
    while (t >= rem) { t -= rem; ++bi; --rem; }
    int bj = bi + t;
    int rowA0 = bi * BM, rowB0 = bj * BM;

    int tid = threadIdx.x;
    int w = tid >> 6, lane = tid & 63;
    int wr = w >> 1, wc = w & 1;
    int l15 = lane & 15, l4 = lane >> 4;

    // Per-lane fragment element offsets (ushort units); +kt*32 per phase.
    int offA[4], offB[4];
    #pragma unroll
    for (int m = 0; m < 4; ++m)
        offA[m] = (rowA0 + wr * 64 + m * 16 + l15) * DIM + l4 * 8;
    #pragma unroll
    for (int n = 0; n < 4; ++n)
        offB[n] = (rowB0 + wc * 64 + n * 16 + l15) * DIM + l4 * 8;

    f32x4 acc[4][4];
    #pragma unroll
    for (int m = 0; m < 4; ++m)
        #pragma unroll
        for (int n = 0; n < 4; ++n)
            acc[m][n] = (f32x4){0.f, 0.f, 0.f, 0.f};

    #pragma unroll 2
    for (int kt = 0; kt < KSTEPS; ++kt) {
        int ko = kt * 32;
        bf16x8 Ah[4], Al[4], Bh[4], Bl[4];
        #pragma unroll
        for (int m = 0; m < 4; ++m) {
            Ah[m] = *(const bf16x8*)(hi + offA[m] + ko);
            Al[m] = *(const bf16x8*)(lo + offA[m] + ko);
        }
        #pragma unroll
        for (int n = 0; n < 4; ++n) {
            Bh[n] = *(const bf16x8*)(hi + offB[n] + ko);
            Bl[n] = *(const bf16x8*)(lo + offB[n] + ko);
        }
        __builtin_amdgcn_s_setprio(1);
        #pragma unroll
        for (int m = 0; m < 4; ++m)
            #pragma unroll
            for (int n = 0; n < 4; ++n) {
                acc[m][n] = __builtin_amdgcn_mfma_f32_16x16x32_bf16(Ah[m], Bh[n], acc[m][n], 0, 0, 0);
                acc[m][n] = __builtin_amdgcn_mfma_f32_16x16x32_bf16(Ah[m], Bl[n], acc[m][n], 0, 0, 0);
                acc[m][n] = __builtin_amdgcn_mfma_f32_16x16x32_bf16(Al[m], Bh[n], acc[m][n], 0, 0, 0);
            }
        __builtin_amdgcn_s_setprio(0);
    }

    // Epilogue. C/D layout (m89-verified): col = lane&15, row = (lane>>4)*4 + reg.
    float cmin[4], sqb_[4];
    #pragma unroll
    for (int n = 0; n < 4; ++n) {
        cmin[n] = FLTMAX;
        sqb_[n] = sq[rowB0 + wc * 64 + n * 16 + l15];
    }
    #pragma unroll
    for (int m = 0; m < 4; ++m) {
        #pragma unroll
        for (int r = 0; r < 4; ++r) {
            int gi = rowA0 + wr * 64 + m * 16 + l4 * 4 + r;
            float sa = sq[gi];
            float rm = FLTMAX;
            #pragma unroll
            for (int n = 0; n < 4; ++n) {
                int gj = rowB0 + wc * 64 + n * 16 + l15;
                float d2 = sa + sqb_[n] - 2.0f * acc[m][n][r];
                d2 = fmaxf(d2, 0.0f);                              // keep uint ordering
                if (((gi - gj) & (NHALF - 1)) == 0) d2 = FLTMAX;   // same label / diag
                rm = fminf(rm, d2);
                cmin[n] = fminf(cmin[n], d2);
            }
            rm = fminf(rm, __shfl_xor(rm, 1));
            rm = fminf(rm, __shfl_xor(rm, 2));
            rm = fminf(rm, __shfl_xor(rm, 4));
            rm = fminf(rm, __shfl_xor(rm, 8));
            if (l15 == 0) atomicMin(&minb[gi], __float_as_uint(rm));
        }
    }
    #pragma unroll
    for (int n = 0; n < 4; ++n) {
        cmin[n] = fminf(cmin[n], __shfl_xor(cmin[n], 16));
        cmin[n] = fminf(cmin[n], __shfl_xor(cmin[n], 32));
    }
    if (l4 == 0) {
        #pragma unroll
        for (int n = 0; n < 4; ++n)
            atomicMin(&minb[rowB0 + wc * 64 + n * 16 + l15], __float_as_uint(cmin[n]));
    }

    // Last-block-done finalize.
    __syncthreads();
    if (tid == 0) {
        __threadfence();
        finflag = atomicAdd(cnt, 1u);
    }
    __syncthreads();
    if (finflag != NTRI - 1) return;

    float sum_diff = 0.f, sum_rel = 0.f, sum_sq = 0.f, cnt_rel = 0.f, cnt_good = 0.f;
    for (int i = tid; i < NTOT; i += 256) {
        unsigned int mb = atomicOr(&minb[i], 0u);   // coherent read
        float hn = fmaxf(sqrtf(fmaxf(__uint_as_float(mb), 1e-14f)), 1e-7f);
        float hp = fmaxf(sqrtf(fmaxf(hp_d2[i], 1e-14f)), 1e-7f);
        float diff = hp - hn;
        float tt = fmaxf(diff + 0.1f, 0.0f);
        sum_diff += diff;
        sum_sq += sq[i];
        if (tt < 1e-5f) cnt_good += 1.0f;
        if (tt > 1e-5f) { cnt_rel += 1.0f; sum_rel += tt; }
    }
    red[0 * 256 + tid] = sum_diff; red[1 * 256 + tid] = sum_rel;
    red[2 * 256 + tid] = sum_sq;   red[3 * 256 + tid] = cnt_rel;
    red[4 * 256 + tid] = cnt_good;
    __syncthreads();
    for (int s = 128; s > 0; s >>= 1) {
        if (tid < s) {
            #pragma unroll
            for (int q = 0; q < 5; ++q) red[q * 256 + tid] += red[q * 256 + tid + s];
        }
        __syncthreads();
    }
    if (tid == 0) {
        float nrel = fmaxf(red[3 * 256], 1.0f);
        out[0] = red[1 * 256] / nrel;               // loss
        out[1] = red[0 * 256] / (float)NTOT;        // mean(differences)
        out[2] = red[4 * 256];                      // good
        out[3] = (float)NTOT - red[4 * 256];        // bad
        out[4] = sqrtf(red[2 * 256] / (float)NTOT); // sqrt(mean norm^2)
    }
}

extern "C" void kernel_launch(void* const* d_in, const int* in_sizes, int n_in,
                              void* d_out, int out_size, void* d_ws, size_t ws_size,
                              hipStream_t stream) {
    const float* h1 = (const float*)d_in[0];
    const float* h2 = (const float*)d_in[1];
    // d_in[2] (h3) unused by the reference.

    char* ws = (char*)d_ws;
    float* sq = (float*)ws;                               // 16 KB
    float* hp_d2 = (float*)(ws + 16384);                  // 16 KB
    unsigned int* minb = (unsigned int*)(ws + 32768);     // 16 KB
    unsigned int* cnt = (unsigned int*)(ws + 49152);      // 4 B (16 KB slot)
    ushort* hi = (ushort*)(ws + 65536);                   // 4 MB
    ushort* lo = hi + (size_t)NTOT * DIM;                 // 4 MB (contiguous after hi)
    float* out = (float*)d_out;

    prep_kernel<<<NHALF / 4, 256, 0, stream>>>(h1, h2, sq, hp_d2, minb, cnt, hi, lo);
    pairmin_mfma<<<NTRI, 256, 0, stream>>>(hi, lo, sq, hp_d2, minb, cnt, out);
}

// Round 6
// 135.527 us; speedup vs baseline: 1.3949x; 1.3949x over previous
//
#include <hip/hip_runtime.h>
#include <hip/hip_bf16.h>
#include <float.h>
#include <math.h>

// BatchHardTripletLoss on MI355X — bf16x3 MFMA gram, double-buffered LDS with
// COUNTED-vmcnt pipeline (never drain to 0 in the main loop), raw s_barrier,
// XCD-swizzled triangular tiles, fused last-block finalize. 2 launches.
// dot(a,b) ~= hi.hi + hi.lo + lo.hi (fp32 MFMA accum) — bitwise-validated R3-R5.

#define NTOT 4096
#define NHALF 2048
#define DIM 512
#define BM 128
#define BKE 32                         // k-elems per phase
#define KSTEPS 16                      // 512 / 32
#define NTILE 32
#define NTRI 528                       // 32*33/2 = 8 * 66
#define FLTMAX 3.402823466e+38f
#define ROW_USH 64                     // 128 B per row-entry: 8 slots x 16 B
#define PHASE_USH (256 * ROW_USH)      // 256 rows (128 A + 128 B) = 32 KB

typedef __attribute__((ext_vector_type(8))) short bf16x8;
typedef __attribute__((ext_vector_type(4))) float f32x4;
typedef __attribute__((ext_vector_type(8))) unsigned short ushort8;

#define GLLDS(gp, lp) __builtin_amdgcn_global_load_lds(                              \
    (const __attribute__((address_space(1))) void*)(gp),                             \
    (__attribute__((address_space(3))) void*)(lp), 16, 0, 0)

__device__ __forceinline__ ushort bf16hi_bits(float x, float* hf) {
    __hip_bfloat16 b = __float2bfloat16(x);
    *hf = __bfloat162float(b);
    return *reinterpret_cast<ushort*>(&b);
}
__device__ __forceinline__ ushort bf16_bits(float x) {
    __hip_bfloat16 b = __float2bfloat16(x);
    return *reinterpret_cast<ushort*>(&b);
}

// One wave per row-pair i: sq, exact partner d2, hi/lo split (16B stores),
// minb init, cnt zero. Lane owns 8 contiguous cols per row.
__global__ __launch_bounds__(256) void prep_kernel(const float* __restrict__ h1,
                                                   const float* __restrict__ h2,
                                                   float* __restrict__ sq,
                                                   float* __restrict__ hp_d2,
                                                   unsigned int* __restrict__ minb,
                                                   unsigned int* __restrict__ cnt,
                                                   ushort* __restrict__ hi,
                                                   ushort* __restrict__ lo) {
    if (blockIdx.x == 0 && threadIdx.x == 0) *cnt = 0u;
    int wv = threadIdx.x >> 6, lane = threadIdx.x & 63;
    int i = blockIdx.x * 4 + wv;
    if (i >= NHALF) return;
    if (lane < 2) minb[i + lane * NHALF] = 0x7F800000u;  // +inf bits

    const float4* r1 = (const float4*)(h1 + (size_t)i * DIM);
    const float4* r2 = (const float4*)(h2 + (size_t)i * DIM);
    float4 a0 = r1[lane * 2], a1 = r1[lane * 2 + 1];   // cols lane*8 .. lane*8+7
    float4 b0 = r2[lane * 2], b1 = r2[lane * 2 + 1];

    float s1 = a0.x*a0.x + a0.y*a0.y + a0.z*a0.z + a0.w*a0.w
             + a1.x*a1.x + a1.y*a1.y + a1.z*a1.z + a1.w*a1.w;
    float s2 = b0.x*b0.x + b0.y*b0.y + b0.z*b0.z + b0.w*b0.w
             + b1.x*b1.x + b1.y*b1.y + b1.z*b1.z + b1.w*b1.w;
    float s12 = a0.x*b0.x + a0.y*b0.y + a0.z*b0.z + a0.w*b0.w
              + a1.x*b1.x + a1.y*b1.y + a1.z*b1.z + a1.w*b1.w;

    {
        float fa[8] = {a0.x, a0.y, a0.z, a0.w, a1.x, a1.y, a1.z, a1.w};
        float fb[8] = {b0.x, b0.y, b0.z, b0.w, b1.x, b1.y, b1.z, b1.w};
        ushort8 ha, la, hb, lb;
        float hf;
        #pragma unroll
        for (int j = 0; j < 8; ++j) {
            ha[j] = bf16hi_bits(fa[j], &hf); la[j] = bf16_bits(fa[j] - hf);
            hb[j] = bf16hi_bits(fb[j], &hf); lb[j] = bf16_bits(fb[j] - hf);
        }
        size_t o1 = (size_t)i * DIM + lane * 8;
        size_t o2 = (size_t)(i + NHALF) * DIM + lane * 8;
        *(ushort8*)(hi + o1) = ha;
        *(ushort8*)(lo + o1) = la;
        *(ushort8*)(hi + o2) = hb;
        *(ushort8*)(lo + o2) = lb;
    }

    #pragma unroll
    for (int m = 1; m < 64; m <<= 1) {
        s1  += __shfl_xor(s1, m);
        s2  += __shfl_xor(s2, m);
        s12 += __shfl_xor(s12, m);
    }
    if (lane == 0) {
        sq[i] = s1;
        sq[i + NHALF] = s2;
        float pd = s1 + s2 - 2.0f * s12;
        hp_d2[i] = pd;
        hp_d2[i + NHALF] = pd;
    }
}

// 528 triangular 128x128 tiles; 4 waves (2x2), wave tile 64x64 (4x4 frags of
// 16x16x32 bf16, 3 MFMA each). LDS: 2 phase buffers x [256 rows][8x16B slots]
// = 64 KB, XOR-(row&7) slot swizzle, linear GLLDS dest + pre-swizzled source.
// Counted-vmcnt schedule: 2 phases in flight; wait vmcnt(8) (own stage for the
// current phase) before barrier; restage freed buffer after compute barrier.
__global__ __launch_bounds__(256, 2) void pairmin_mfma(const ushort* __restrict__ hi,
                                                       const ushort* __restrict__ lo,
                                                       const float* __restrict__ sq,
                                                       const float* __restrict__ hp_d2,
                                                       unsigned int* __restrict__ minb,
                                                       unsigned int* __restrict__ cnt,
                                                       float* __restrict__ out) {
    __shared__ ushort lds[2 * PHASE_USH] __attribute__((aligned(16)));
    __shared__ unsigned int finflag;

    // bijective XCD swizzle: 528 = 8 * 66; neighbors on one XCD share A-panels
    int bid = blockIdx.x;
    int t = (bid & 7) * (NTRI / 8) + (bid >> 3);
    int bi = 0, rem = NTILE;
    while (t >= rem) { t -= rem; ++bi; --rem; }
    int bj = bi + t;
    int rowA0 = bi * BM, rowB0 = bj * BM;

    int tid = threadIdx.x;
    int w = tid >> 6, lane = tid & 63;
    int wr = w >> 1, wc = w & 1;
    int l15 = lane & 15, l4 = lane >> 4;

    // Stage sources: 8 GLLDS/wave/phase, each 1 KB (8 rows x 128 B).
    // LDS[row][slot] holds global chunk slot ^ (row&7); chunks 0-3 hi, 4-7 lo.
    int rloc = lane >> 3, ccol = lane & 7;
    int sg = ccol ^ rloc;
    const ushort* sbase = (sg & 4) ? lo : hi;
    int sc = sg & 3;
    const ushort* srcp[8];
    #pragma unroll
    for (int j = 0; j < 8; ++j) {
        int brow = w * 64 + j * 8 + rloc;                  // 0..255
        int grow = (brow < BM) ? (rowA0 + brow) : (rowB0 + brow - BM);
        srcp[j] = sbase + (size_t)grow * DIM + sc * 8;
    }
    ushort* dst0 = &lds[w * 4096];                         // wave's quarter, buf 0

    f32x4 acc[4][4];
    #pragma unroll
    for (int m = 0; m < 4; ++m)
        #pragma unroll
        for (int n = 0; n < 4; ++n)
            acc[m][n] = (f32x4){0.f, 0.f, 0.f, 0.f};

    auto STAGE = [&](int kt, ushort* dwave) {
        #pragma unroll
        for (int j = 0; j < 8; ++j)
            GLLDS(srcp[j] + kt * BKE, dwave + j * 512);
    };
    auto COMPUTE = [&](const ushort* base) {
        bf16x8 Ah[4], Al[4], Bh[4], Bl[4];
        #pragma unroll
        for (int m = 0; m < 4; ++m) {
            int r = wr * 64 + m * 16 + l15;
            const ushort* rp = base + r * ROW_USH;
            Ah[m] = *(const bf16x8*)(rp + ((l4 ^ (r & 7)) << 3));
            Al[m] = *(const bf16x8*)(rp + (((l4 | 4) ^ (r & 7)) << 3));
        }
        #pragma unroll
        for (int n = 0; n < 4; ++n) {
            int r = wc * 64 + n * 16 + l15;
            const ushort* rp = base + (BM + r) * ROW_USH;
            Bh[n] = *(const bf16x8*)(rp + ((l4 ^ (r & 7)) << 3));
            Bl[n] = *(const bf16x8*)(rp + (((l4 | 4) ^ (r & 7)) << 3));
        }
        __builtin_amdgcn_s_setprio(1);
        #pragma unroll
        for (int m = 0; m < 4; ++m)
            #pragma unroll
            for (int n = 0; n < 4; ++n) {
                acc[m][n] = __builtin_amdgcn_mfma_f32_16x16x32_bf16(Ah[m], Bh[n], acc[m][n], 0, 0, 0);
                acc[m][n] = __builtin_amdgcn_mfma_f32_16x16x32_bf16(Ah[m], Bl[n], acc[m][n], 0, 0, 0);
                acc[m][n] = __builtin_amdgcn_mfma_f32_16x16x32_bf16(Al[m], Bh[n], acc[m][n], 0, 0, 0);
            }
        __builtin_amdgcn_s_setprio(0);
    };

    // Prologue: phases 0 and 1 in flight (16 outstanding per wave).
    STAGE(0, dst0);
    STAGE(1, dst0 + PHASE_USH);
    for (int kt = 0; kt < KSTEPS - 1; ++kt) {
        asm volatile("s_waitcnt vmcnt(8)" ::: "memory");   // own stage of phase kt landed
        __builtin_amdgcn_sched_barrier(0);
        __builtin_amdgcn_s_barrier();                      // all waves: buffer kt&1 ready
        __builtin_amdgcn_sched_barrier(0);
        COMPUTE(lds + (kt & 1) * PHASE_USH);
        __builtin_amdgcn_s_barrier();                      // all waves done reading
        __builtin_amdgcn_sched_barrier(0);
        if (kt < KSTEPS - 2)
            STAGE(kt + 2, dst0 + (kt & 1) * PHASE_USH);    // refill freed buffer
    }
    asm volatile("s_waitcnt vmcnt(0)" ::: "memory");       // final phase drain
    __builtin_amdgcn_sched_barrier(0);
    __builtin_amdgcn_s_barrier();
    __builtin_amdgcn_sched_barrier(0);
    COMPUTE(lds + PHASE_USH);                              // phase 15 -> buffer 1

    // Epilogue. C/D layout (m89-verified): col = lane&15, row = (lane>>4)*4 + reg.
    float cmin[4], sqb_[4];
    #pragma unroll
    for (int n = 0; n < 4; ++n) {
        cmin[n] = FLTMAX;
        sqb_[n] = sq[rowB0 + wc * 64 + n * 16 + l15];
    }
    #pragma unroll
    for (int m = 0; m < 4; ++m) {
        #pragma unroll
        for (int r = 0; r < 4; ++r) {
            int gi = rowA0 + wr * 64 + m * 16 + l4 * 4 + r;
            float sa = sq[gi];
            float rm = FLTMAX;
            #pragma unroll
            for (int n = 0; n < 4; ++n) {
                int gj = rowB0 + wc * 64 + n * 16 + l15;
                float d2 = sa + sqb_[n] - 2.0f * acc[m][n][r];
                d2 = fmaxf(d2, 0.0f);                              // keep uint ordering
                if (((gi - gj) & (NHALF - 1)) == 0) d2 = FLTMAX;   // same label / diag
                rm = fminf(rm, d2);
                cmin[n] = fminf(cmin[n], d2);
            }
            rm = fminf(rm, __shfl_xor(rm, 1));
            rm = fminf(rm, __shfl_xor(rm, 2));
            rm = fminf(rm, __shfl_xor(rm, 4));
            rm = fminf(rm, __shfl_xor(rm, 8));
            if (l15 == 0) atomicMin(&minb[gi], __float_as_uint(rm));
        }
    }
    #pragma unroll
    for (int n = 0; n < 4; ++n) {
        cmin[n] = fminf(cmin[n], __shfl_xor(cmin[n], 16));
        cmin[n] = fminf(cmin[n], __shfl_xor(cmin[n], 32));
    }
    if (l4 == 0) {
        #pragma unroll
        for (int n = 0; n < 4; ++n)
            atomicMin(&minb[rowB0 + wc * 64 + n * 16 + l15], __float_as_uint(cmin[n]));
    }

    // Last-block-done finalize.
    __syncthreads();
    if (tid == 0) {
        __threadfence();
        finflag = atomicAdd(cnt, 1u);
    }
    __syncthreads();
    if (finflag != NTRI - 1) return;

    float* red = (float*)lds;             // reuse LDS: [5][256]
    float sum_diff = 0.f, sum_rel = 0.f, sum_sq = 0.f, cnt_rel = 0.f, cnt_good = 0.f;
    for (int i = tid; i < NTOT; i += 256) {
        unsigned int mb = atomicOr(&minb[i], 0u);   // coherent read
        float hn = fmaxf(sqrtf(fmaxf(__uint_as_float(mb), 1e-14f)), 1e-7f);
        float hp = fmaxf(sqrtf(fmaxf(hp_d2[i], 1e-14f)), 1e-7f);
        float diff = hp - hn;
        float tt = fmaxf(diff + 0.1f, 0.0f);
        sum_diff += diff;
        sum_sq += sq[i];
        if (tt < 1e-5f) cnt_good += 1.0f;
        if (tt > 1e-5f) { cnt_rel += 1.0f; sum_rel += tt; }
    }
    red[0 * 256 + tid] = sum_diff; red[1 * 256 + tid] = sum_rel;
    red[2 * 256 + tid] = sum_sq;   red[3 * 256 + tid] = cnt_rel;
    red[4 * 256 + tid] = cnt_good;
    __syncthreads();
    for (int s = 128; s > 0; s >>= 1) {
        if (tid < s) {
            #pragma unroll
            for (int q = 0; q < 5; ++q) red[q * 256 + tid] += red[q * 256 + tid + s];
        }
        __syncthreads();
    }
    if (tid == 0) {
        float nrel = fmaxf(red[3 * 256], 1.0f);
        out[0] = red[1 * 256] / nrel;               // loss
        out[1] = red[0 * 256] / (float)NTOT;        // mean(differences)
        out[2] = red[4 * 256];                      // good
        out[3] = (float)NTOT - red[4 * 256];        // bad
        out[4] = sqrtf(red[2 * 256] / (float)NTOT); // sqrt(mean norm^2)
    }
}

extern "C" void kernel_launch(void* const* d_in, const int* in_sizes, int n_in,
                              void* d_out, int out_size, void* d_ws, size_t ws_size,
                              hipStream_t stream) {
    const float* h1 = (const float*)d_in[0];
    const float* h2 = (const float*)d_in[1];
    // d_in[2] (h3) unused by the reference.

    char* ws = (char*)d_ws;
    float* sq = (float*)ws;                               // 16 KB
    float* hp_d2 = (float*)(ws + 16384);                  // 16 KB
    unsigned int* minb = (unsigned int*)(ws + 32768);     // 16 KB
    unsigned int* cnt = (unsigned int*)(ws + 49152);      // 4 B (16 KB slot)
    ushort* hi = (ushort*)(ws + 65536);                   // 4 MB
    ushort* lo = hi + (size_t)NTOT * DIM;                 // 4 MB
    float* out = (float*)d_out;

    prep_kernel<<<NHALF / 4, 256, 0, stream>>>(h1, h2, sq, hp_d2, minb, cnt, hi, lo);
    pairmin_mfma<<<NTRI, 256, 0, stream>>>(hi, lo, sq, hp_d2, minb, cnt, out);
}

// Round 7
// 131.088 us; speedup vs baseline: 1.4421x; 1.0339x over previous
//
#include <hip/hip_runtime.h>
#include <hip/hip_bf16.h>
#include <float.h>
#include <math.h>

// BatchHardTripletLoss on MI355X — bf16x3 MFMA gram with FRAGMENT-MAJOR global
// layout: each 16x16x32-operand fragment is a contiguous 1KB lane-linear block.
// A-operands: direct global->VGPR (coalesced 1KB loads, L2-hot).
// B-operands: GLLDS identity-copy into 32KB LDS (conflict-free by construction).
// 3 blocks/CU, all 528 triangular tiles resident (no dispatch rounds, no tail).
// dot(a,b) ~= hi.hi + hi.lo + lo.hi (fp32 MFMA accum) — validated R3-R6.

#define NTOT 4096
#define NHALF 2048
#define DIM 512
#define BM 128
#define KT 8                         // k-steps of 64 elems
#define NTILE 32
#define NTRI 528                     // 32*33/2 = 8 * 66
#define FLTMAX 3.402823466e+38f
#define FRAGBLK 512                  // ushorts per fragment block (1 KB)
#define F_KT (32 * FRAGBLK)          // per (panel,kt): 8 fr x 2 ksl x 2 hl = 32 KB
#define F_PANEL (8 * F_KT)           // per 128-row panel: 256 KB

typedef __attribute__((ext_vector_type(8))) short bf16x8;
typedef __attribute__((ext_vector_type(4))) float f32x4;
typedef __attribute__((ext_vector_type(8))) unsigned short ushort8;

#define GLLDS(gp, lp) __builtin_amdgcn_global_load_lds(                              \
    (const __attribute__((address_space(1))) void*)(gp),                             \
    (__attribute__((address_space(3))) void*)(lp), 16, 0, 0)

__device__ __forceinline__ ushort bf16hi_bits(float x, float* hf) {
    __hip_bfloat16 b = __float2bfloat16(x);
    *hf = __bfloat162float(b);
    return *reinterpret_cast<ushort*>(&b);
}
__device__ __forceinline__ ushort bf16_bits(float x) {
    __hip_bfloat16 b = __float2bfloat16(x);
    return *reinterpret_cast<ushort*>(&b);
}

__device__ __forceinline__ int fragoff(int fr, int ksl, int hl) {
    return ((fr * 2 + ksl) * 2 + hl) * FRAGBLK;
}

// Wave job (gp, fr): convert 16 rows of panel gp into F-layout; gp<16 waves also
// compute sq / partner-d2 stats (reading the h2 partner slice redundantly).
// 64 blocks x 4 waves = 256 jobs. Also: minb init + cnt zero.
__global__ __launch_bounds__(256) void prep_kernel(const float* __restrict__ h1,
                                                   const float* __restrict__ h2,
                                                   float* __restrict__ sq,
                                                   float* __restrict__ hp_d2,
                                                   unsigned int* __restrict__ minb,
                                                   unsigned int* __restrict__ cnt,
                                                   ushort* __restrict__ F) {
    int tid = threadIdx.x;
    int g = blockIdx.x * 256 + tid;
    if (g < NTOT) minb[g] = 0x7F800000u;   // +inf bits
    if (g == 0) *cnt = 0u;

    int job = blockIdx.x * 4 + (tid >> 6);   // 0..255
    int lane = tid & 63, l15 = lane & 15, l4 = lane >> 4;
    int gp = job >> 3, fr = job & 7;         // panel 0..31, fragrow 0..7
    bool isA = (gp < 16);                    // h1-side panel
    int prow = (gp & 15) * BM + fr * 16 + l15;   // row within its half [0,2048)
    const float* r1 = (isA ? h1 : h2) + (size_t)prow * DIM;
    const float* r2 = h2 + (size_t)prow * DIM;   // partner row (used if isA)

    float s1 = 0.f, s2 = 0.f, s12 = 0.f;
    size_t pbase = (size_t)gp * F_PANEL;

    #pragma unroll 2
    for (int kt = 0; kt < KT; ++kt) {
        #pragma unroll
        for (int ksl = 0; ksl < 2; ++ksl) {
            int c = kt * 64 + ksl * 32 + l4 * 8;
            float4 x0 = *(const float4*)(r1 + c);
            float4 x1 = *(const float4*)(r1 + c + 4);
            float xs[8] = {x0.x, x0.y, x0.z, x0.w, x1.x, x1.y, x1.z, x1.w};
            ushort8 hv, lv;
            float hf;
            #pragma unroll
            for (int j = 0; j < 8; ++j) {
                hv[j] = bf16hi_bits(xs[j], &hf);
                lv[j] = bf16_bits(xs[j] - hf);
                s1 = fmaf(xs[j], xs[j], s1);
            }
            size_t fb = pbase + kt * F_KT + fragoff(fr, ksl, 0) + lane * 8;
            *(ushort8*)(F + fb) = hv;
            *(ushort8*)(F + fb + FRAGBLK) = lv;
            if (isA) {
                float4 y0 = *(const float4*)(r2 + c);
                float4 y1 = *(const float4*)(r2 + c + 4);
                float ys[8] = {y0.x, y0.y, y0.z, y0.w, y1.x, y1.y, y1.z, y1.w};
                #pragma unroll
                for (int j = 0; j < 8; ++j) {
                    s2 = fmaf(ys[j], ys[j], s2);
                    s12 = fmaf(xs[j], ys[j], s12);
                }
            }
        }
    }
    // reduce over the 4 l4-groups (lanes {l15, +16, +32, +48})
    s1 += __shfl_xor(s1, 16);  s1 += __shfl_xor(s1, 32);
    s2 += __shfl_xor(s2, 16);  s2 += __shfl_xor(s2, 32);
    s12 += __shfl_xor(s12, 16); s12 += __shfl_xor(s12, 32);
    if (l4 == 0) {
        if (isA) {
            sq[prow] = s1;
            float pd = s1 + s2 - 2.0f * s12;
            hp_d2[prow] = pd;
            hp_d2[prow + NHALF] = pd;
        } else {
            sq[prow + NHALF] = s1;   // this wave's s1 == ||h2 row||^2
        }
    }
}

// 528 triangular 128x128 tiles, all resident at 3 blocks/CU. 4 waves (2x2),
// wave tile 64x64 = 4x4 frags of 16x16x32 bf16, 3 MFMA each (hh, hl, lh).
// Per kt: barrier; GLLDS B-panel (identity 32KB copy, 8x1KB per wave);
// 16 coalesced 1KB A-loads to VGPR; barrier (drains both); MFMA cluster.
__global__ __launch_bounds__(256, 3) void pairmin_mfma(const ushort* __restrict__ F,
                                                       const float* __restrict__ sq,
                                                       const float* __restrict__ hp_d2,
                                                       unsigned int* __restrict__ minb,
                                                       unsigned int* __restrict__ cnt,
                                                       float* __restrict__ out) {
    __shared__ ushort Blds[F_KT] __attribute__((aligned(16)));   // 32 KB
    __shared__ float red[5 * 256];
    __shared__ unsigned int finflag;

    // bijective XCD swizzle (528 = 8 * 66) + triangular decode, bi <= bj
    int bid = blockIdx.x;
    int t = (bid & 7) * (NTRI / 8) + (bid >> 3);
    int bi = 0, rem = NTILE;
    while (t >= rem) { t -= rem; ++bi; --rem; }
    int bj = bi + t;
    int rowA0 = bi * BM, rowB0 = bj * BM;

    int tid = threadIdx.x;
    int w = tid >> 6, lane = tid & 63;
    int wr = w >> 1, wc = w & 1;
    int l15 = lane & 15, l4 = lane >> 4;

    const ushort* FA = F + (size_t)bi * F_PANEL;
    const ushort* FB = F + (size_t)bj * F_PANEL;

    f32x4 acc[4][4];
    #pragma unroll
    for (int m = 0; m < 4; ++m)
        #pragma unroll
        for (int n = 0; n < 4; ++n)
            acc[m][n] = (f32x4){0.f, 0.f, 0.f, 0.f};

    for (int kt = 0; kt < KT; ++kt) {
        __syncthreads();                       // prev-kt B reads done
        const ushort* fbk = FB + kt * F_KT;
        #pragma unroll
        for (int j = 0; j < 8; ++j)
            GLLDS(fbk + (w * 8 + j) * FRAGBLK + lane * 8,
                  Blds + (w * 8 + j) * FRAGBLK);
        const ushort* fak = FA + kt * F_KT;
        bf16x8 a[16];
        #pragma unroll
        for (int m = 0; m < 4; ++m)
            #pragma unroll
            for (int ksl = 0; ksl < 2; ++ksl) {
                a[(m * 2 + ksl) * 2 + 0] =
                    *(const bf16x8*)(fak + fragoff(wr * 4 + m, ksl, 0) + lane * 8);
                a[(m * 2 + ksl) * 2 + 1] =
                    *(const bf16x8*)(fak + fragoff(wr * 4 + m, ksl, 1) + lane * 8);
            }
        __builtin_amdgcn_sched_barrier(0);     // loads issued before the drain
        __syncthreads();                       // vmcnt(0): B visible, A landed
        __builtin_amdgcn_s_setprio(1);
        #pragma unroll
        for (int ksl = 0; ksl < 2; ++ksl) {
            bf16x8 Bh[4], Bl[4];
            #pragma unroll
            for (int n = 0; n < 4; ++n) {
                int fo = fragoff(wc * 4 + n, ksl, 0) + lane * 8;
                Bh[n] = *(const bf16x8*)&Blds[fo];
                Bl[n] = *(const bf16x8*)&Blds[fo + FRAGBLK];
            }
            #pragma unroll
            for (int m = 0; m < 4; ++m) {
                bf16x8 Ah = a[(m * 2 + ksl) * 2 + 0];
                bf16x8 Al = a[(m * 2 + ksl) * 2 + 1];
                #pragma unroll
                for (int n = 0; n < 4; ++n) {
                    acc[m][n] = __builtin_amdgcn_mfma_f32_16x16x32_bf16(Ah, Bh[n], acc[m][n], 0, 0, 0);
                    acc[m][n] = __builtin_amdgcn_mfma_f32_16x16x32_bf16(Ah, Bl[n], acc[m][n], 0, 0, 0);
                    acc[m][n] = __builtin_amdgcn_mfma_f32_16x16x32_bf16(Al, Bh[n], acc[m][n], 0, 0, 0);
                }
            }
        }
        __builtin_amdgcn_s_setprio(0);
    }

    // Epilogue. C/D layout (m89-verified): col = lane&15, row = (lane>>4)*4 + reg.
    float cmin[4], sqb_[4];
    #pragma unroll
    for (int n = 0; n < 4; ++n) {
        cmin[n] = FLTMAX;
        sqb_[n] = sq[rowB0 + wc * 64 + n * 16 + l15];
    }
    #pragma unroll
    for (int m = 0; m < 4; ++m) {
        #pragma unroll
        for (int r = 0; r < 4; ++r) {
            int gi = rowA0 + wr * 64 + m * 16 + l4 * 4 + r;
            float sa = sq[gi];
            float rm = FLTMAX;
            #pragma unroll
            for (int n = 0; n < 4; ++n) {
                int gj = rowB0 + wc * 64 + n * 16 + l15;
                float d2 = sa + sqb_[n] - 2.0f * acc[m][n][r];
                d2 = fmaxf(d2, 0.0f);                              // keep uint ordering
                if (((gi - gj) & (NHALF - 1)) == 0) d2 = FLTMAX;   // same label / diag
                rm = fminf(rm, d2);
                cmin[n] = fminf(cmin[n], d2);
            }
            rm = fminf(rm, __shfl_xor(rm, 1));
            rm = fminf(rm, __shfl_xor(rm, 2));
            rm = fminf(rm, __shfl_xor(rm, 4));
            rm = fminf(rm, __shfl_xor(rm, 8));
            if (l15 == 0) atomicMin(&minb[gi], __float_as_uint(rm));
        }
    }
    #pragma unroll
    for (int n = 0; n < 4; ++n) {
        cmin[n] = fminf(cmin[n], __shfl_xor(cmin[n], 16));
        cmin[n] = fminf(cmin[n], __shfl_xor(cmin[n], 32));
    }
    if (l4 == 0) {
        #pragma unroll
        for (int n = 0; n < 4; ++n)
            atomicMin(&minb[rowB0 + wc * 64 + n * 16 + l15], __float_as_uint(cmin[n]));
    }

    // Last-block-done finalize.
    __syncthreads();
    if (tid == 0) {
        __threadfence();
        finflag = atomicAdd(cnt, 1u);
    }
    __syncthreads();
    if (finflag != NTRI - 1) return;

    float sum_diff = 0.f, sum_rel = 0.f, sum_sq = 0.f, cnt_rel = 0.f, cnt_good = 0.f;
    for (int i = tid; i < NTOT; i += 256) {
        unsigned int mb = atomicOr(&minb[i], 0u);   // coherent read
        float hn = fmaxf(sqrtf(fmaxf(__uint_as_float(mb), 1e-14f)), 1e-7f);
        float hp = fmaxf(sqrtf(fmaxf(hp_d2[i], 1e-14f)), 1e-7f);
        float diff = hp - hn;
        float tt = fmaxf(diff + 0.1f, 0.0f);
        sum_diff += diff;
        sum_sq += sq[i];
        if (tt < 1e-5f) cnt_good += 1.0f;
        if (tt > 1e-5f) { cnt_rel += 1.0f; sum_rel += tt; }
    }
    red[0 * 256 + tid] = sum_diff; red[1 * 256 + tid] = sum_rel;
    red[2 * 256 + tid] = sum_sq;   red[3 * 256 + tid] = cnt_rel;
    red[4 * 256 + tid] = cnt_good;
    __syncthreads();
    for (int s = 128; s > 0; s >>= 1) {
        if (tid < s) {
            #pragma unroll
            for (int q = 0; q < 5; ++q) red[q * 256 + tid] += red[q * 256 + tid + s];
        }
        __syncthreads();
    }
    if (tid == 0) {
        float nrel = fmaxf(red[3 * 256], 1.0f);
        out[0] = red[1 * 256] / nrel;               // loss
        out[1] = red[0 * 256] / (float)NTOT;        // mean(differences)
        out[2] = red[4 * 256];                      // good
        out[3] = (float)NTOT - red[4 * 256];        // bad
        out[4] = sqrtf(red[2 * 256] / (float)NTOT); // sqrt(mean norm^2)
    }
}

extern "C" void kernel_launch(void* const* d_in, const int* in_sizes, int n_in,
                              void* d_out, int out_size, void* d_ws, size_t ws_size,
                              hipStream_t stream) {
    const float* h1 = (const float*)d_in[0];
    const float* h2 = (const float*)d_in[1];
    // d_in[2] (h3) unused by the reference.

    char* ws = (char*)d_ws;
    float* sq = (float*)ws;                               // 16 KB
    float* hp_d2 = (float*)(ws + 16384);                  // 16 KB
    unsigned int* minb = (unsigned int*)(ws + 32768);     // 16 KB
    unsigned int* cnt = (unsigned int*)(ws + 49152);      // 4 B (16 KB slot)
    ushort* F = (ushort*)(ws + 65536);                    // 8 MB fragment-major
    float* out = (float*)d_out;

    prep_kernel<<<64, 256, 0, stream>>>(h1, h2, sq, hp_d2, minb, cnt, F);
    pairmin_mfma<<<NTRI, 256, 0, stream>>>(F, sq, hp_d2, minb, cnt, out);
}